// Round 1
// baseline (404.623 us; speedup 1.0000x reference)
//
#include <hip/hip_runtime.h>
#include <hip/hip_bf16.h>

// ---------------------------------------------------------------------------
// TransformerBlock: LN1 -> QKV -> leaky-relu attention -> Wo+res -> LN2 ->
//                   FFN1(leaky) -> FFN2+res
// B=2 N=2048 EMB=1024 H=16 HD=64 FFN=4096. All GEMMs bf16 MFMA 16x16x32,
// m97-style 128x128 tile, global_load_lds(16B) staging, f32 accumulate.
// ---------------------------------------------------------------------------

typedef unsigned short u16;
typedef __bf16 bf16x8 __attribute__((ext_vector_type(8)));
typedef float f32x4 __attribute__((ext_vector_type(4)));
typedef unsigned short u16x8 __attribute__((ext_vector_type(8)));

typedef const __attribute__((address_space(1))) void* as1cv;
typedef __attribute__((address_space(3))) void* as3v;

#define MFMA16(a, b, c) __builtin_amdgcn_mfma_f32_16x16x32_bf16((a), (b), (c), 0, 0, 0)
#define GLL16(g, l) __builtin_amdgcn_global_load_lds((as1cv)(g), (as3v)(l), 16, 0, 0)

__device__ __forceinline__ u16 f2bf(float f) {
  unsigned u = __builtin_bit_cast(unsigned, f);
  u += 0x7fffu + ((u >> 16) & 1u);   // RNE
  return (u16)(u >> 16);
}
__device__ __forceinline__ float lrelu(float v) { return v >= 0.f ? v : 0.01f * v; }

// ------------------- weight f32 -> bf16 (Wq,Wk,Wv,Wo = 1M each; W1,W2 = 4M) --
__global__ __launch_bounds__(256) void cvt6(
    const float* __restrict__ p0, const float* __restrict__ p1,
    const float* __restrict__ p2, const float* __restrict__ p3,
    const float* __restrict__ p4, const float* __restrict__ p5,
    u16* __restrict__ o0, u16* __restrict__ o1, u16* __restrict__ o2,
    u16* __restrict__ o3, u16* __restrict__ o4, u16* __restrict__ o5)
{
  int i = blockIdx.x * 256 + threadIdx.x;   // unit = 8 elements
  const float* src; u16* dst; int off;
  if (i < 4 * 131072) {
    int s = i >> 17; off = i & 131071;
    src = (s == 0) ? p0 : (s == 1) ? p1 : (s == 2) ? p2 : p3;
    dst = (s == 0) ? o0 : (s == 1) ? o1 : (s == 2) ? o2 : o3;
  } else {
    int j = i - 4 * 131072;
    int s = j >> 19; off = j & 524287;
    src = s ? p5 : p4;
    dst = s ? o5 : o4;
  }
  const float4* s4 = (const float4*)src;
  float4 a = s4[(size_t)off * 2], b = s4[(size_t)off * 2 + 1];
  u16x8 o = { f2bf(a.x), f2bf(a.y), f2bf(a.z), f2bf(a.w),
              f2bf(b.x), f2bf(b.y), f2bf(b.z), f2bf(b.w) };
  *(u16x8*)(dst + (size_t)off * 8) = o;
}

// ------------------- LayerNorm row (1024) f32 -> bf16 ----------------------
__global__ __launch_bounds__(256) void ln_k(
    const float* __restrict__ x, const float* __restrict__ g,
    const float* __restrict__ bb, u16* __restrict__ out)
{
  const int tid = threadIdx.x;
  const int row = blockIdx.x;
  const float4* xr = (const float4*)(x + (size_t)row * 1024);
  float4 v = xr[tid];
  float s  = v.x + v.y + v.z + v.w;
  float s2 = v.x*v.x + v.y*v.y + v.z*v.z + v.w*v.w;
#pragma unroll
  for (int o = 32; o > 0; o >>= 1) { s += __shfl_down(s, o, 64); s2 += __shfl_down(s2, o, 64); }
  __shared__ float sh[8];
  if ((tid & 63) == 0) { sh[tid >> 6] = s; sh[4 + (tid >> 6)] = s2; }
  __syncthreads();
  s  = sh[0] + sh[1] + sh[2] + sh[3];
  s2 = sh[4] + sh[5] + sh[6] + sh[7];
  float mu  = s * (1.0f / 1024.0f);
  float var = s2 * (1.0f / 1024.0f) - mu * mu;
  float rs  = rsqrtf(var + 1e-6f);
  float4 gv = ((const float4*)g)[tid];
  float4 bv = ((const float4*)bb)[tid];
  ushort4 o;
  o.x = f2bf((v.x - mu) * rs * gv.x + bv.x);
  o.y = f2bf((v.y - mu) * rs * gv.y + bv.y);
  o.z = f2bf((v.z - mu) * rs * gv.z + bv.z);
  o.w = f2bf((v.w - mu) * rs * gv.w + bv.w);
  ((ushort4*)out)[(size_t)row * 256 + tid] = o;
}

// ------------------- GEMM core: C[128,128] tile, A[M,K] x W[N,K]^T ---------
// 256 threads = 4 waves (2x2 of 64x64). BK=32. LDS linear, global_load_lds 16B.
__device__ __forceinline__ void gemm_core128(
    const u16* __restrict__ A, const u16* __restrict__ W, int K,
    int row0, int wrow0, u16* lsA, u16* lsB, f32x4 (&acc)[4][4])
{
  const int tid  = threadIdx.x;
  const int lane = tid & 63, wave = tid >> 6;
  const int wr = wave >> 1, wc = wave & 1;
  const int lr = lane & 15, lg = lane >> 4;

  const u16* ga0 = A + (size_t)(row0 + (tid >> 2)) * K + (tid & 3) * 8;
  const u16* ga1 = ga0 + (size_t)64 * K;
  const u16* gb0 = W + (size_t)(wrow0 + (tid >> 2)) * K + (tid & 3) * 8;
  const u16* gb1 = gb0 + (size_t)64 * K;
  u16* la0 = lsA + tid * 8;          // byte offset tid*16 (linear, wave-contig)
  u16* la1 = lsA + 2048 + tid * 8;
  u16* lb0 = lsB + tid * 8;
  u16* lb1 = lsB + 2048 + tid * 8;

  for (int k0 = 0; k0 < K; k0 += 32) {
    GLL16(ga0, la0); GLL16(ga1, la1);
    GLL16(gb0, lb0); GLL16(gb1, lb1);
    ga0 += 32; ga1 += 32; gb0 += 32; gb1 += 32;
    __syncthreads();
    bf16x8 av[4], bv[4];
#pragma unroll
    for (int mi = 0; mi < 4; mi++)
      av[mi] = *reinterpret_cast<const bf16x8*>(lsA + (wr * 64 + mi * 16 + lr) * 32 + lg * 8);
#pragma unroll
    for (int ni = 0; ni < 4; ni++)
      bv[ni] = *reinterpret_cast<const bf16x8*>(lsB + (wc * 64 + ni * 16 + lr) * 32 + lg * 8);
#pragma unroll
    for (int mi = 0; mi < 4; mi++)
#pragma unroll
      for (int ni = 0; ni < 4; ni++)
        acc[mi][ni] = MFMA16(av[mi], bv[ni], acc[mi][ni]);
    __syncthreads();
  }
}

// ------------------- fused QKV GEMM: N=3072, scatter epilogue --------------
__global__ __launch_bounds__(256, 2) void gemm_qkv(
    const u16* __restrict__ xn,
    const u16* __restrict__ Wq, const u16* __restrict__ Wk, const u16* __restrict__ Wv,
    const float* __restrict__ bq, const float* __restrict__ bk, const float* __restrict__ bv,
    u16* __restrict__ qb, u16* __restrict__ kb, u16* __restrict__ vtb)
{
  __shared__ u16 lsA[128 * 32];
  __shared__ u16 lsB[128 * 32];
  const int mt = blockIdx.x / 24, nt = blockIdx.x % 24;
  const int row0 = mt * 128, col0 = nt * 128;
  const int sel = col0 >> 10, c0 = col0 & 1023;
  const u16* W = (sel == 0) ? Wq : (sel == 1) ? Wk : Wv;
  const float* bias = (sel == 0) ? bq : (sel == 1) ? bk : bv;

  f32x4 acc[4][4];
  f32x4 z = {0.f, 0.f, 0.f, 0.f};
#pragma unroll
  for (int mi = 0; mi < 4; mi++)
#pragma unroll
    for (int ni = 0; ni < 4; ni++) acc[mi][ni] = z;

  gemm_core128(xn, W, 1024, row0, c0, lsA, lsB, acc);

  const int lane = threadIdx.x & 63, wave = threadIdx.x >> 6;
  const int wr = wave >> 1, wc = wave & 1;
  const int lr = lane & 15, lg = lane >> 4;
#pragma unroll
  for (int ni = 0; ni < 4; ni++) {
    int c = c0 + wc * 64 + ni * 16 + lr;        // 0..1023 within selected proj
    float bsv = bias[c];
    int h = c >> 6, hd = c & 63;
#pragma unroll
    for (int mi = 0; mi < 4; mi++) {
      int rbase = row0 + wr * 64 + mi * 16 + lg * 4;   // global row (4-aligned)
      int b = rbase >> 11;
      int n = rbase & 2047;
      if (sel < 2) {                 // q,k -> [B,H,N,HD]
        u16* dst = (sel == 0) ? qb : kb;
        size_t base = ((size_t)(b * 16 + h) * 2048 + n) * 64 + hd;
#pragma unroll
        for (int r = 0; r < 4; r++)
          dst[base + (size_t)r * 64] = f2bf(acc[mi][ni][r] + bsv);
      } else {                       // v -> transposed [B,H,HD,N]
        size_t base = ((size_t)((b * 16 + h) * 64 + hd)) * 2048 + n;
        ushort4 o;
        o.x = f2bf(acc[mi][ni][0] + bsv);
        o.y = f2bf(acc[mi][ni][1] + bsv);
        o.z = f2bf(acc[mi][ni][2] + bsv);
        o.w = f2bf(acc[mi][ni][3] + bsv);
        *(ushort4*)(vtb + base) = o;
      }
    }
  }
}

// ------------------- generic GEMM + epilogue -------------------------------
// EPI 0: outf[idx] = acc + bias + extra[idx]           (f32; Wo+res, FFN2+res)
// EPI 1: outh[idx] = bf16(lrelu(acc + bias))           (FFN1)
template <int EPI>
__global__ __launch_bounds__(256, 2) void gemm128(
    const u16* __restrict__ A, const u16* __restrict__ W,
    const float* __restrict__ bias, float* __restrict__ outf,
    u16* __restrict__ outh, const float* __restrict__ extra,
    int K, int nTiles)
{
  __shared__ u16 lsA[128 * 32];
  __shared__ u16 lsB[128 * 32];
  const int mt = blockIdx.x / nTiles, nt = blockIdx.x % nTiles;
  const int row0 = mt * 128, col0 = nt * 128;

  f32x4 acc[4][4];
  f32x4 z = {0.f, 0.f, 0.f, 0.f};
#pragma unroll
  for (int mi = 0; mi < 4; mi++)
#pragma unroll
    for (int ni = 0; ni < 4; ni++) acc[mi][ni] = z;

  gemm_core128(A, W, K, row0, col0, lsA, lsB, acc);

  const int N = nTiles * 128;
  const int lane = threadIdx.x & 63, wave = threadIdx.x >> 6;
  const int wr = wave >> 1, wc = wave & 1;
  const int lr = lane & 15, lg = lane >> 4;
#pragma unroll
  for (int ni = 0; ni < 4; ni++) {
    int col = col0 + wc * 64 + ni * 16 + lr;
    float bsv = bias[col];
#pragma unroll
    for (int mi = 0; mi < 4; mi++) {
      int rbase = row0 + wr * 64 + mi * 16 + lg * 4;
#pragma unroll
      for (int r = 0; r < 4; r++) {
        float v = acc[mi][ni][r] + bsv;
        size_t idx = (size_t)(rbase + r) * N + col;
        if (EPI == 0) {
          outf[idx] = v + extra[idx];
        } else {
          outh[idx] = f2bf(lrelu(v));
        }
      }
    }
  }
}

// ------------------- fused leaky-relu attention ----------------------------
// grid = (B*H)*(N/128) blocks; block handles one head x 128 q-rows.
// ctx = lrelu(Q K^T / 8) @ V, V pre-transposed [HD,N] so PV is BT-form too.
// LDS XOR-swizzle: col ^= (row&7)<<3  (16B granules) -> conflict-free b128.
__device__ __forceinline__ int swz(int row, int col) {
  return row * 64 + (col ^ ((row & 7) << 3));
}

__global__ __launch_bounds__(256, 3) void attn_k(
    const u16* __restrict__ qb, const u16* __restrict__ kb,
    const u16* __restrict__ vtb, u16* __restrict__ ctx)
{
  __shared__ u16 lq[128 * 64];
  __shared__ u16 lk[64 * 64];
  __shared__ u16 lv[64 * 64];
  __shared__ u16 lp[128 * 64];

  const int tid = threadIdx.x;
  const int lane = tid & 63, wave = tid >> 6;
  const int wr = wave >> 1, wc = wave & 1;
  const int lr = lane & 15, lg = lane >> 4;
  const int bh = blockIdx.x >> 4, qt = blockIdx.x & 15;
  const int n0 = qt * 128;
  const u16* qh = qb + (size_t)bh * 2048 * 64;
  const u16* kh = kb + (size_t)bh * 2048 * 64;
  const u16* vh = vtb + (size_t)bh * 64 * 2048;

  // stage Q tile [128][64] (reg-staged, swizzled)
  {
    int r = tid >> 3, kk = (tid & 7) * 8;
#pragma unroll
    for (int j = 0; j < 4; j++)
      *(u16x8*)(lq + swz(j * 32 + r, kk)) =
          *(const u16x8*)(qh + (size_t)(n0 + j * 32 + r) * 64 + kk);
  }

  f32x4 z = {0.f, 0.f, 0.f, 0.f};
  f32x4 cacc[4][2];
#pragma unroll
  for (int mi = 0; mi < 4; mi++)
#pragma unroll
    for (int ni = 0; ni < 2; ni++) cacc[mi][ni] = z;

  for (int kt = 0; kt < 32; kt++) {
    {  // stage K [64][64] and Vt [64][64] for this k-tile
      int r = tid >> 3, kk = (tid & 7) * 8;
#pragma unroll
      for (int j = 0; j < 2; j++) {
        *(u16x8*)(lk + swz(j * 32 + r, kk)) =
            *(const u16x8*)(kh + (size_t)(kt * 64 + j * 32 + r) * 64 + kk);
        *(u16x8*)(lv + swz(j * 32 + r, kk)) =
            *(const u16x8*)(vh + (size_t)(j * 32 + r) * 2048 + kt * 64 + kk);
      }
    }
    __syncthreads();

    // S = Q K^T  (wave: q-rows wr*64+, k-cols wc*32+)
    f32x4 sacc[4][2];
#pragma unroll
    for (int mi = 0; mi < 4; mi++)
#pragma unroll
      for (int ni = 0; ni < 2; ni++) sacc[mi][ni] = z;
#pragma unroll
    for (int ks = 0; ks < 2; ks++) {
      bf16x8 aq[4], bk8[2];
#pragma unroll
      for (int mi = 0; mi < 4; mi++)
        aq[mi] = *reinterpret_cast<const bf16x8*>(lq + swz(wr * 64 + mi * 16 + lr, ks * 32 + lg * 8));
#pragma unroll
      for (int ni = 0; ni < 2; ni++)
        bk8[ni] = *reinterpret_cast<const bf16x8*>(lk + swz(wc * 32 + ni * 16 + lr, ks * 32 + lg * 8));
#pragma unroll
      for (int mi = 0; mi < 4; mi++)
#pragma unroll
        for (int ni = 0; ni < 2; ni++)
          sacc[mi][ni] = MFMA16(aq[mi], bk8[ni], sacc[mi][ni]);
    }
    // P = lrelu(S/8) -> LDS bf16
#pragma unroll
    for (int mi = 0; mi < 4; mi++)
#pragma unroll
      for (int ni = 0; ni < 2; ni++)
#pragma unroll
        for (int r = 0; r < 4; r++) {
          float v = lrelu(sacc[mi][ni][r] * 0.125f);
          int i = wr * 64 + mi * 16 + lg * 4 + r;
          int j = wc * 32 + ni * 16 + lr;
          lp[swz(i, j)] = f2bf(v);
        }
    __syncthreads();

    // ctx += P @ V  (BT-form vs Vt; wave: q-rows wr*64+, d-cols wc*32+)
#pragma unroll
    for (int js = 0; js < 2; js++) {
      bf16x8 pa[4], vb[2];
#pragma unroll
      for (int mi = 0; mi < 4; mi++)
        pa[mi] = *reinterpret_cast<const bf16x8*>(lp + swz(wr * 64 + mi * 16 + lr, js * 32 + lg * 8));
#pragma unroll
      for (int ni = 0; ni < 2; ni++)
        vb[ni] = *reinterpret_cast<const bf16x8*>(lv + swz(wc * 32 + ni * 16 + lr, js * 32 + lg * 8));
#pragma unroll
      for (int mi = 0; mi < 4; mi++)
#pragma unroll
        for (int ni = 0; ni < 2; ni++)
          cacc[mi][ni] = MFMA16(pa[mi], vb[ni], cacc[mi][ni]);
    }
    __syncthreads();
  }

  // write ctx back merged: [B,N,H*HD] row-major
  const int b = bh >> 4, h = bh & 15;
#pragma unroll
  for (int mi = 0; mi < 4; mi++)
#pragma unroll
    for (int ni = 0; ni < 2; ni++)
#pragma unroll
      for (int r = 0; r < 4; r++) {
        int n = n0 + wr * 64 + mi * 16 + lg * 4 + r;
        int d = wc * 32 + ni * 16 + lr;
        ctx[((size_t)(b * 2048 + n)) * 1024 + h * 64 + d] = f2bf(cacc[mi][ni][r]);
      }
}

// ---------------------------------------------------------------------------
extern "C" void kernel_launch(void* const* d_in, const int* in_sizes, int n_in,
                              void* d_out, int out_size, void* d_ws, size_t ws_size,
                              hipStream_t stream) {
  (void)in_sizes; (void)n_in; (void)out_size; (void)ws_size;
  const float* x    = (const float*)d_in[0];
  const float* ln1g = (const float*)d_in[1];
  const float* ln1b = (const float*)d_in[2];
  const float* ln2g = (const float*)d_in[3];
  const float* ln2b = (const float*)d_in[4];
  const float* Wq = (const float*)d_in[5];  const float* bq = (const float*)d_in[6];
  const float* Wk = (const float*)d_in[7];  const float* bk = (const float*)d_in[8];
  const float* Wv = (const float*)d_in[9];  const float* bv = (const float*)d_in[10];
  const float* Wo = (const float*)d_in[11]; const float* bo = (const float*)d_in[12];
  const float* W1 = (const float*)d_in[13]; const float* b1 = (const float*)d_in[14];
  const float* W2 = (const float*)d_in[15]; const float* b2 = (const float*)d_in[16];

  char* ws = (char*)d_ws;
  // workspace map (120 MiB total)
  u16*   WqB  = (u16*)(ws + ((size_t)0 << 20));
  u16*   WkB  = (u16*)(ws + ((size_t)2 << 20));
  u16*   WvB  = (u16*)(ws + ((size_t)4 << 20));
  u16*   WoB  = (u16*)(ws + ((size_t)6 << 20));
  u16*   W1B  = (u16*)(ws + ((size_t)8 << 20));
  u16*   W2B  = (u16*)(ws + ((size_t)16 << 20));
  u16*   xn1  = (u16*)(ws + ((size_t)24 << 20));
  u16*   qb   = (u16*)(ws + ((size_t)32 << 20));
  u16*   kb   = (u16*)(ws + ((size_t)40 << 20));
  u16*   vtb  = (u16*)(ws + ((size_t)48 << 20));
  u16*   ctxb = (u16*)(ws + ((size_t)56 << 20));
  float* x2   = (float*)(ws + ((size_t)64 << 20));
  u16*   xn2  = (u16*)(ws + ((size_t)80 << 20));
  u16*   ff1  = (u16*)(ws + ((size_t)88 << 20));

  dim3 blk(256);

  cvt6<<<dim3(6144), blk, 0, stream>>>(Wq, Wk, Wv, Wo, W1, W2,
                                       WqB, WkB, WvB, WoB, W1B, W2B);
  ln_k<<<dim3(4096), blk, 0, stream>>>(x, ln1g, ln1b, xn1);
  gemm_qkv<<<dim3(768), blk, 0, stream>>>(xn1, WqB, WkB, WvB, bq, bk, bv,
                                          qb, kb, vtb);
  attn_k<<<dim3(512), blk, 0, stream>>>(qb, kb, vtb, ctxb);
  // Wo projection + residual -> x2 (f32)
  gemm128<0><<<dim3(256), blk, 0, stream>>>(ctxb, WoB, bo, x2, (u16*)nullptr, x,
                                            1024, 8);
  ln_k<<<dim3(4096), blk, 0, stream>>>(x2, ln2g, ln2b, xn2);
  // FFN1 + leaky -> ff1 (bf16)
  gemm128<1><<<dim3(1024), blk, 0, stream>>>(xn2, W1B, b1, (float*)nullptr, ff1,
                                             (const float*)nullptr, 1024, 32);
  // FFN2 + residual -> out (f32)
  gemm128<0><<<dim3(256), blk, 0, stream>>>(ff1, W2B, b2, (float*)d_out,
                                            (u16*)nullptr, x2, 4096, 8);
}

// Round 2
// 353.350 us; speedup vs baseline: 1.1451x; 1.1451x over previous
//
#include <hip/hip_runtime.h>
#include <hip/hip_bf16.h>

// ---------------------------------------------------------------------------
// TransformerBlock: LN1 -> QKV -> leaky-relu attention -> Wo+res -> LN2 ->
//                   FFN1(leaky) -> FFN2+res
// B=2 N=2048 EMB=1024 H=16 HD=64 FFN=4096. bf16 MFMA 16x16x32, 128x128 tile,
// 2-phase double-buffered global_load_lds(16B) pipeline, f32 accumulate.
// FFN2 split-K=4 (bf16 partials) + fused reduce. XCD-aware grid swizzle.
// ---------------------------------------------------------------------------

typedef unsigned short u16;
typedef __bf16 bf16x8 __attribute__((ext_vector_type(8)));
typedef float f32x4 __attribute__((ext_vector_type(4)));
typedef unsigned short u16x8 __attribute__((ext_vector_type(8)));

typedef const __attribute__((address_space(1))) void* as1cv;
typedef __attribute__((address_space(3))) void* as3v;

#define MFMA16(a, b, c) __builtin_amdgcn_mfma_f32_16x16x32_bf16((a), (b), (c), 0, 0, 0)
#define GLL16(g, l) __builtin_amdgcn_global_load_lds((as1cv)(g), (as3v)(l), 16, 0, 0)

__device__ __forceinline__ u16 f2bf(float f) {
  unsigned u = __builtin_bit_cast(unsigned, f);
  u += 0x7fffu + ((u >> 16) & 1u);   // RNE
  return (u16)(u >> 16);
}
__device__ __forceinline__ float bf2f(u16 u) {
  return __builtin_bit_cast(float, ((unsigned)u) << 16);
}
__device__ __forceinline__ float lrelu(float v) { return v >= 0.f ? v : 0.01f * v; }

// XCD-aware bijective swizzle (nwg % 8 == 0): XCD x gets contiguous work chunk.
__device__ __forceinline__ int xcds(int bid, int nwg) {
  int cpx = nwg >> 3;
  return (bid & 7) * cpx + (bid >> 3);
}

// ------------------- weight f32 -> bf16 (Wq,Wk,Wv,Wo = 1M each; W1,W2 = 4M) --
__global__ __launch_bounds__(256) void cvt6(
    const float* __restrict__ p0, const float* __restrict__ p1,
    const float* __restrict__ p2, const float* __restrict__ p3,
    const float* __restrict__ p4, const float* __restrict__ p5,
    u16* __restrict__ o0, u16* __restrict__ o1, u16* __restrict__ o2,
    u16* __restrict__ o3, u16* __restrict__ o4, u16* __restrict__ o5)
{
  int i = blockIdx.x * 256 + threadIdx.x;   // unit = 8 elements
  const float* src; u16* dst; int off;
  if (i < 4 * 131072) {
    int s = i >> 17; off = i & 131071;
    src = (s == 0) ? p0 : (s == 1) ? p1 : (s == 2) ? p2 : p3;
    dst = (s == 0) ? o0 : (s == 1) ? o1 : (s == 2) ? o2 : o3;
  } else {
    int j = i - 4 * 131072;
    int s = j >> 19; off = j & 524287;
    src = s ? p5 : p4;
    dst = s ? o5 : o4;
  }
  const float4* s4 = (const float4*)src;
  float4 a = s4[(size_t)off * 2], b = s4[(size_t)off * 2 + 1];
  u16x8 o = { f2bf(a.x), f2bf(a.y), f2bf(a.z), f2bf(a.w),
              f2bf(b.x), f2bf(b.y), f2bf(b.z), f2bf(b.w) };
  *(u16x8*)(dst + (size_t)off * 8) = o;
}

// ------------------- LayerNorm row (1024) f32 -> bf16 ----------------------
__global__ __launch_bounds__(256) void ln_k(
    const float* __restrict__ x, const float* __restrict__ g,
    const float* __restrict__ bb, u16* __restrict__ out)
{
  const int tid = threadIdx.x;
  const int row = blockIdx.x;
  const float4* xr = (const float4*)(x + (size_t)row * 1024);
  float4 v = xr[tid];
  float s  = v.x + v.y + v.z + v.w;
  float s2 = v.x*v.x + v.y*v.y + v.z*v.z + v.w*v.w;
#pragma unroll
  for (int o = 32; o > 0; o >>= 1) { s += __shfl_down(s, o, 64); s2 += __shfl_down(s2, o, 64); }
  __shared__ float sh[8];
  if ((tid & 63) == 0) { sh[tid >> 6] = s; sh[4 + (tid >> 6)] = s2; }
  __syncthreads();
  s  = sh[0] + sh[1] + sh[2] + sh[3];
  s2 = sh[4] + sh[5] + sh[6] + sh[7];
  float mu  = s * (1.0f / 1024.0f);
  float var = s2 * (1.0f / 1024.0f) - mu * mu;
  float rs  = rsqrtf(var + 1e-6f);
  float4 gv = ((const float4*)g)[tid];
  float4 bv = ((const float4*)bb)[tid];
  ushort4 o;
  o.x = f2bf((v.x - mu) * rs * gv.x + bv.x);
  o.y = f2bf((v.y - mu) * rs * gv.y + bv.y);
  o.z = f2bf((v.z - mu) * rs * gv.z + bv.z);
  o.w = f2bf((v.w - mu) * rs * gv.w + bv.w);
  ((ushort4*)out)[(size_t)row * 256 + tid] = o;
}

// ------------------- GEMM core: C[128,128] tile, A[M,K] x W[N,K]^T ---------
// 256 threads = 4 waves (2x2 of 64x64). BK=32. 2-phase double-buffered LDS:
// stage tile t+1 BEFORE compute of tile t; one vmcnt(0)+barrier per K-step.
__device__ __forceinline__ void gemm_core128(
    const u16* __restrict__ A, const u16* __restrict__ W,
    int kstride, int klen,
    int row0, int wrow0, u16* lsA, u16* lsB, f32x4 (&acc)[4][4])
{
  const int tid  = threadIdx.x;
  const int lane = tid & 63, wave = tid >> 6;
  const int wr = wave >> 1, wc = wave & 1;
  const int lr = lane & 15, lg = lane >> 4;

  const u16* ga0 = A + (size_t)(row0 + (tid >> 2)) * kstride + (tid & 3) * 8;
  const u16* ga1 = ga0 + (size_t)64 * kstride;
  const u16* gb0 = W + (size_t)(wrow0 + (tid >> 2)) * kstride + (tid & 3) * 8;
  const u16* gb1 = gb0 + (size_t)64 * kstride;
  u16* la = lsA + tid * 8;            // linear, wave-contiguous (GLL dest rule)
  u16* lb = lsB + tid * 8;

  // prologue: stage K-step 0 into buffer 0
  GLL16(ga0, la); GLL16(ga1, la + 2048);
  GLL16(gb0, lb); GLL16(gb1, lb + 2048);
  ga0 += 32; ga1 += 32; gb0 += 32; gb1 += 32;
  __syncthreads();

  const int nsteps = klen >> 5;
  int cur = 0;
  for (int t = 0; t < nsteps; t++) {
    int nxt = cur ^ 1;
    if (t + 1 < nsteps) {             // issue next-tile loads (stay in flight
      GLL16(ga0, la + nxt * 4096);    //  until this iteration's barrier)
      GLL16(ga1, la + nxt * 4096 + 2048);
      GLL16(gb0, lb + nxt * 4096);
      GLL16(gb1, lb + nxt * 4096 + 2048);
      ga0 += 32; ga1 += 32; gb0 += 32; gb1 += 32;
    }
    const u16* cA = lsA + cur * 4096;
    const u16* cB = lsB + cur * 4096;
    bf16x8 av[4], bv[4];
#pragma unroll
    for (int mi = 0; mi < 4; mi++)
      av[mi] = *reinterpret_cast<const bf16x8*>(cA + (wr * 64 + mi * 16 + lr) * 32 + lg * 8);
#pragma unroll
    for (int ni = 0; ni < 4; ni++)
      bv[ni] = *reinterpret_cast<const bf16x8*>(cB + (wc * 64 + ni * 16 + lr) * 32 + lg * 8);
#pragma unroll
    for (int mi = 0; mi < 4; mi++)
#pragma unroll
      for (int ni = 0; ni < 4; ni++)
        acc[mi][ni] = MFMA16(av[mi], bv[ni], acc[mi][ni]);
    __syncthreads();                  // drains vmcnt(0): next buffer ready
    cur = nxt;
  }
}

// ------------------- fused QKV GEMM: N=3072, scatter epilogue --------------
__global__ __launch_bounds__(256, 4) void gemm_qkv(
    const u16* __restrict__ xn,
    const u16* __restrict__ Wq, const u16* __restrict__ Wk, const u16* __restrict__ Wv,
    const float* __restrict__ bq, const float* __restrict__ bk, const float* __restrict__ bv,
    u16* __restrict__ qb, u16* __restrict__ kb, u16* __restrict__ vtb)
{
  __shared__ u16 lsA[2 * 128 * 32];
  __shared__ u16 lsB[2 * 128 * 32];
  const int wid = xcds(blockIdx.x, 768);
  const int mt = wid / 24, nt = wid % 24;
  const int row0 = mt * 128, col0 = nt * 128;
  const int sel = col0 >> 10, c0 = col0 & 1023;
  const u16* W = (sel == 0) ? Wq : (sel == 1) ? Wk : Wv;
  const float* bias = (sel == 0) ? bq : (sel == 1) ? bk : bv;

  f32x4 acc[4][4];
  f32x4 z = {0.f, 0.f, 0.f, 0.f};
#pragma unroll
  for (int mi = 0; mi < 4; mi++)
#pragma unroll
    for (int ni = 0; ni < 4; ni++) acc[mi][ni] = z;

  gemm_core128(xn, W, 1024, 1024, row0, c0, lsA, lsB, acc);

  const int lane = threadIdx.x & 63, wave = threadIdx.x >> 6;
  const int wr = wave >> 1, wc = wave & 1;
  const int lr = lane & 15, lg = lane >> 4;
#pragma unroll
  for (int ni = 0; ni < 4; ni++) {
    int c = c0 + wc * 64 + ni * 16 + lr;        // 0..1023 within selected proj
    float bsv = bias[c];
    int h = c >> 6, hd = c & 63;
#pragma unroll
    for (int mi = 0; mi < 4; mi++) {
      int rbase = row0 + wr * 64 + mi * 16 + lg * 4;   // global row (4-aligned)
      int b = rbase >> 11;
      int n = rbase & 2047;
      if (sel < 2) {                 // q,k -> [B,H,N,HD]
        u16* dst = (sel == 0) ? qb : kb;
        size_t base = ((size_t)(b * 16 + h) * 2048 + n) * 64 + hd;
#pragma unroll
        for (int r = 0; r < 4; r++)
          dst[base + (size_t)r * 64] = f2bf(acc[mi][ni][r] + bsv);
      } else {                       // v -> transposed [B,H,HD,N]
        size_t base = ((size_t)((b * 16 + h) * 64 + hd)) * 2048 + n;
        ushort4 o;
        o.x = f2bf(acc[mi][ni][0] + bsv);
        o.y = f2bf(acc[mi][ni][1] + bsv);
        o.z = f2bf(acc[mi][ni][2] + bsv);
        o.w = f2bf(acc[mi][ni][3] + bsv);
        *(ushort4*)(vtb + base) = o;
      }
    }
  }
}

// ------------------- generic GEMM + epilogue -------------------------------
// EPI 0: outf[idx] = acc + bias + extra[idx]           (f32; Wo+res)
// EPI 1: outh[idx] = bf16(lrelu(acc + bias))           (FFN1)
template <int EPI>
__global__ __launch_bounds__(256, 4) void gemm128(
    const u16* __restrict__ A, const u16* __restrict__ W,
    const float* __restrict__ bias, float* __restrict__ outf,
    u16* __restrict__ outh, const float* __restrict__ extra,
    int K, int nTiles, int nwg)
{
  __shared__ u16 lsA[2 * 128 * 32];
  __shared__ u16 lsB[2 * 128 * 32];
  const int wid = xcds(blockIdx.x, nwg);
  const int mt = wid / nTiles, nt = wid % nTiles;
  const int row0 = mt * 128, col0 = nt * 128;

  f32x4 acc[4][4];
  f32x4 z = {0.f, 0.f, 0.f, 0.f};
#pragma unroll
  for (int mi = 0; mi < 4; mi++)
#pragma unroll
    for (int ni = 0; ni < 4; ni++) acc[mi][ni] = z;

  gemm_core128(A, W, K, K, row0, col0, lsA, lsB, acc);

  const int N = nTiles * 128;
  const int lane = threadIdx.x & 63, wave = threadIdx.x >> 6;
  const int wr = wave >> 1, wc = wave & 1;
  const int lr = lane & 15, lg = lane >> 4;
#pragma unroll
  for (int ni = 0; ni < 4; ni++) {
    int col = col0 + wc * 64 + ni * 16 + lr;
    float bsv = bias[col];
#pragma unroll
    for (int mi = 0; mi < 4; mi++) {
      int rbase = row0 + wr * 64 + mi * 16 + lg * 4;
#pragma unroll
      for (int r = 0; r < 4; r++) {
        float v = acc[mi][ni][r] + bsv;
        size_t idx = (size_t)(rbase + r) * N + col;
        if (EPI == 0) {
          outf[idx] = v + extra[idx];
        } else {
          outh[idx] = f2bf(lrelu(v));
        }
      }
    }
  }
}

// ------------------- FFN2 split-K GEMM: 4 chunks of K=1024 -----------------
// grid 1024 = 4 chunks x (32 mt x 8 nt). Partials bf16, no bias.
__global__ __launch_bounds__(256, 4) void gemm_ffn2(
    const u16* __restrict__ A, const u16* __restrict__ W,
    u16* __restrict__ pout)
{
  __shared__ u16 lsA[2 * 128 * 32];
  __shared__ u16 lsB[2 * 128 * 32];
  const int wid = xcds(blockIdx.x, 1024);
  const int chunk = wid >> 8, rem = wid & 255;
  const int mt = rem >> 3, nt = rem & 7;
  const int row0 = mt * 128, col0 = nt * 128;

  f32x4 acc[4][4];
  f32x4 z = {0.f, 0.f, 0.f, 0.f};
#pragma unroll
  for (int mi = 0; mi < 4; mi++)
#pragma unroll
    for (int ni = 0; ni < 4; ni++) acc[mi][ni] = z;

  gemm_core128(A + chunk * 1024, W + chunk * 1024, 4096, 1024,
               row0, col0, lsA, lsB, acc);

  u16* out = pout + (size_t)chunk * (4096 * 1024);
  const int lane = threadIdx.x & 63, wave = threadIdx.x >> 6;
  const int wr = wave >> 1, wc = wave & 1;
  const int lr = lane & 15, lg = lane >> 4;
#pragma unroll
  for (int ni = 0; ni < 4; ni++) {
    int col = col0 + wc * 64 + ni * 16 + lr;
#pragma unroll
    for (int mi = 0; mi < 4; mi++) {
      int rbase = row0 + wr * 64 + mi * 16 + lg * 4;
#pragma unroll
      for (int r = 0; r < 4; r++)
        out[(size_t)(rbase + r) * 1024 + col] = f2bf(acc[mi][ni][r]);
    }
  }
}

// ------------------- FFN2 reduce: out = sum(4 partials) + b2 + x2 ----------
__global__ __launch_bounds__(256) void reduce_ffn2(
    const u16* __restrict__ p, const float* __restrict__ b2,
    const float* __restrict__ x2, float* __restrict__ out)
{
  size_t i = ((size_t)blockIdx.x * 256 + threadIdx.x) * 4;
  int col = (int)(i & 1023);
  ushort4 a0 = *(const ushort4*)(p + i);
  ushort4 a1 = *(const ushort4*)(p + (size_t)(4096 * 1024) + i);
  ushort4 a2 = *(const ushort4*)(p + (size_t)(2 * 4096 * 1024) + i);
  ushort4 a3 = *(const ushort4*)(p + (size_t)(3 * 4096 * 1024) + i);
  float4 bv = *(const float4*)(b2 + col);
  float4 xv = *(const float4*)(x2 + i);
  float4 r;
  r.x = bf2f(a0.x) + bf2f(a1.x) + bf2f(a2.x) + bf2f(a3.x) + bv.x + xv.x;
  r.y = bf2f(a0.y) + bf2f(a1.y) + bf2f(a2.y) + bf2f(a3.y) + bv.y + xv.y;
  r.z = bf2f(a0.z) + bf2f(a1.z) + bf2f(a2.z) + bf2f(a3.z) + bv.z + xv.z;
  r.w = bf2f(a0.w) + bf2f(a1.w) + bf2f(a2.w) + bf2f(a3.w) + bv.w + xv.w;
  *(float4*)(out + i) = r;
}

// ------------------- fused leaky-relu attention ----------------------------
// grid = (B*H)*(N/128) blocks; block handles one head x 128 q-rows.
// ctx = lrelu(Q K^T / 8) @ V, V pre-transposed [HD,N] so PV is BT-form too.
// LDS XOR-swizzle: col ^= (row&7)<<3  (16B granules) -> conflict-free b128.
__device__ __forceinline__ int swz(int row, int col) {
  return row * 64 + (col ^ ((row & 7) << 3));
}

__global__ __launch_bounds__(256, 3) void attn_k(
    const u16* __restrict__ qb, const u16* __restrict__ kb,
    const u16* __restrict__ vtb, u16* __restrict__ ctx)
{
  __shared__ u16 lq[128 * 64];
  __shared__ u16 lk[64 * 64];
  __shared__ u16 lv[64 * 64];
  __shared__ u16 lp[128 * 64];

  const int tid = threadIdx.x;
  const int lane = tid & 63, wave = tid >> 6;
  const int wr = wave >> 1, wc = wave & 1;
  const int lr = lane & 15, lg = lane >> 4;
  const int wid = xcds(blockIdx.x, 512);
  const int bh = wid >> 4, qt = wid & 15;
  const int n0 = qt * 128;
  const u16* qh = qb + (size_t)bh * 2048 * 64;
  const u16* kh = kb + (size_t)bh * 2048 * 64;
  const u16* vh = vtb + (size_t)bh * 64 * 2048;

  // stage Q tile [128][64] (reg-staged, swizzled)
  {
    int r = tid >> 3, kk = (tid & 7) * 8;
#pragma unroll
    for (int j = 0; j < 4; j++)
      *(u16x8*)(lq + swz(j * 32 + r, kk)) =
          *(const u16x8*)(qh + (size_t)(n0 + j * 32 + r) * 64 + kk);
  }

  f32x4 z = {0.f, 0.f, 0.f, 0.f};
  f32x4 cacc[4][2];
#pragma unroll
  for (int mi = 0; mi < 4; mi++)
#pragma unroll
    for (int ni = 0; ni < 2; ni++) cacc[mi][ni] = z;

  for (int kt = 0; kt < 32; kt++) {
    {  // stage K [64][64] and Vt [64][64] for this k-tile
      int r = tid >> 3, kk = (tid & 7) * 8;
#pragma unroll
      for (int j = 0; j < 2; j++) {
        *(u16x8*)(lk + swz(j * 32 + r, kk)) =
            *(const u16x8*)(kh + (size_t)(kt * 64 + j * 32 + r) * 64 + kk);
        *(u16x8*)(lv + swz(j * 32 + r, kk)) =
            *(const u16x8*)(vh + (size_t)(j * 32 + r) * 2048 + kt * 64 + kk);
      }
    }
    __syncthreads();

    // S = Q K^T  (wave: q-rows wr*64+, k-cols wc*32+)
    f32x4 sacc[4][2];
#pragma unroll
    for (int mi = 0; mi < 4; mi++)
#pragma unroll
      for (int ni = 0; ni < 2; ni++) sacc[mi][ni] = z;
#pragma unroll
    for (int ks = 0; ks < 2; ks++) {
      bf16x8 aq[4], bk8[2];
#pragma unroll
      for (int mi = 0; mi < 4; mi++)
        aq[mi] = *reinterpret_cast<const bf16x8*>(lq + swz(wr * 64 + mi * 16 + lr, ks * 32 + lg * 8));
#pragma unroll
      for (int ni = 0; ni < 2; ni++)
        bk8[ni] = *reinterpret_cast<const bf16x8*>(lk + swz(wc * 32 + ni * 16 + lr, ks * 32 + lg * 8));
#pragma unroll
      for (int mi = 0; mi < 4; mi++)
#pragma unroll
        for (int ni = 0; ni < 2; ni++)
          sacc[mi][ni] = MFMA16(aq[mi], bk8[ni], sacc[mi][ni]);
    }
    // P = lrelu(S/8) -> LDS bf16
#pragma unroll
    for (int mi = 0; mi < 4; mi++)
#pragma unroll
      for (int ni = 0; ni < 2; ni++)
#pragma unroll
        for (int r = 0; r < 4; r++) {
          float v = lrelu(sacc[mi][ni][r] * 0.125f);
          int i = wr * 64 + mi * 16 + lg * 4 + r;
          int j = wc * 32 + ni * 16 + lr;
          lp[swz(i, j)] = f2bf(v);
        }
    __syncthreads();

    // ctx += P @ V  (BT-form vs Vt; wave: q-rows wr*64+, d-cols wc*32+)
#pragma unroll
    for (int js = 0; js < 2; js++) {
      bf16x8 pa[4], vb[2];
#pragma unroll
      for (int mi = 0; mi < 4; mi++)
        pa[mi] = *reinterpret_cast<const bf16x8*>(lp + swz(wr * 64 + mi * 16 + lr, js * 32 + lg * 8));
#pragma unroll
      for (int ni = 0; ni < 2; ni++)
        vb[ni] = *reinterpret_cast<const bf16x8*>(lv + swz(wc * 32 + ni * 16 + lr, js * 32 + lg * 8));
#pragma unroll
      for (int mi = 0; mi < 4; mi++)
#pragma unroll
        for (int ni = 0; ni < 2; ni++)
          cacc[mi][ni] = MFMA16(pa[mi], vb[ni], cacc[mi][ni]);
    }
    __syncthreads();
  }

  // write ctx back merged: [B,N,H*HD] row-major
  const int b = bh >> 4, h = bh & 15;
#pragma unroll
  for (int mi = 0; mi < 4; mi++)
#pragma unroll
    for (int ni = 0; ni < 2; ni++)
#pragma unroll
      for (int r = 0; r < 4; r++) {
        int n = n0 + wr * 64 + mi * 16 + lg * 4 + r;
        int d = wc * 32 + ni * 16 + lr;
        ctx[((size_t)(b * 2048 + n)) * 1024 + h * 64 + d] = f2bf(cacc[mi][ni][r]);
      }
}

// ---------------------------------------------------------------------------
extern "C" void kernel_launch(void* const* d_in, const int* in_sizes, int n_in,
                              void* d_out, int out_size, void* d_ws, size_t ws_size,
                              hipStream_t stream) {
  (void)in_sizes; (void)n_in; (void)out_size; (void)ws_size;
  const float* x    = (const float*)d_in[0];
  const float* ln1g = (const float*)d_in[1];
  const float* ln1b = (const float*)d_in[2];
  const float* ln2g = (const float*)d_in[3];
  const float* ln2b = (const float*)d_in[4];
  const float* Wq = (const float*)d_in[5];  const float* bq = (const float*)d_in[6];
  const float* Wk = (const float*)d_in[7];  const float* bk = (const float*)d_in[8];
  const float* Wv = (const float*)d_in[9];  const float* bv = (const float*)d_in[10];
  const float* Wo = (const float*)d_in[11]; const float* bo = (const float*)d_in[12];
  const float* W1 = (const float*)d_in[13]; const float* b1 = (const float*)d_in[14];
  const float* W2 = (const float*)d_in[15]; const float* b2 = (const float*)d_in[16];

  char* ws = (char*)d_ws;
  // workspace map (120 MiB high-water, same as round 1):
  //   0..24   weights bf16 (live whole call)
  //   24..56  xn1(8) qb(8) kb(8) vtb(8)   [dead after attn]  -> pF2 aliases
  //   56..64  ctxb(8)                      [dead after Wo]
  //   64..80  x2 f32(16)                   [live to end]
  //   80..88  xn2(8)                       [dead after FFN1]
  //   88..120 ff1(32)                      [written by FFN1; pWo aliases 88..104 before]
  u16*   WqB  = (u16*)(ws + ((size_t)0 << 20));
  u16*   WkB  = (u16*)(ws + ((size_t)2 << 20));
  u16*   WvB  = (u16*)(ws + ((size_t)4 << 20));
  u16*   WoB  = (u16*)(ws + ((size_t)6 << 20));
  u16*   W1B  = (u16*)(ws + ((size_t)8 << 20));
  u16*   W2B  = (u16*)(ws + ((size_t)16 << 20));
  u16*   xn1  = (u16*)(ws + ((size_t)24 << 20));
  u16*   qb   = (u16*)(ws + ((size_t)32 << 20));
  u16*   kb   = (u16*)(ws + ((size_t)40 << 20));
  u16*   vtb  = (u16*)(ws + ((size_t)48 << 20));
  u16*   ctxb = (u16*)(ws + ((size_t)56 << 20));
  float* x2   = (float*)(ws + ((size_t)64 << 20));
  u16*   xn2  = (u16*)(ws + ((size_t)80 << 20));
  u16*   ff1  = (u16*)(ws + ((size_t)88 << 20));
  u16*   pF2  = (u16*)(ws + ((size_t)24 << 20));  // 4 x 8 MiB bf16 partials

  dim3 blk(256);

  cvt6<<<dim3(6144), blk, 0, stream>>>(Wq, Wk, Wv, Wo, W1, W2,
                                       WqB, WkB, WvB, WoB, W1B, W2B);
  ln_k<<<dim3(4096), blk, 0, stream>>>(x, ln1g, ln1b, xn1);
  gemm_qkv<<<dim3(768), blk, 0, stream>>>(xn1, WqB, WkB, WvB, bq, bk, bv,
                                          qb, kb, vtb);
  attn_k<<<dim3(512), blk, 0, stream>>>(qb, kb, vtb, ctxb);
  // Wo projection + residual -> x2 (f32)
  gemm128<0><<<dim3(256), blk, 0, stream>>>(ctxb, WoB, bo, x2, (u16*)nullptr, x,
                                            1024, 8, 256);
  ln_k<<<dim3(4096), blk, 0, stream>>>(x2, ln2g, ln2b, xn2);
  // FFN1 + leaky -> ff1 (bf16)
  gemm128<1><<<dim3(1024), blk, 0, stream>>>(xn2, W1B, b1, (float*)nullptr, ff1,
                                             (const float*)nullptr, 1024, 32, 1024);
  // FFN2 split-K=4 -> bf16 partials, then reduce + bias + residual -> out
  gemm_ffn2<<<dim3(1024), blk, 0, stream>>>(ff1, W2B, pF2);
  reduce_ffn2<<<dim3(4096), blk, 0, stream>>>(pF2, b2, x2, (float*)d_out);
}